// Round 6
// baseline (234.790 us; speedup 1.0000x reference)
//
#include <hip/hip_runtime.h>
#include <cstdio>

// MHA block for MI355X (gfx950). Round 5:
//  - attn: 4-way key split (wave owns 32-key parity, computes all 64 q),
//    halves LDS reads per round; 4-way fp32 merge via LDS overlay.
//  - qkv_gemm: wave = n-slice of all 3 outputs (B-reads deduped).
// ws (bf16): Q[S][768] | K[S][768] | Vt[768][S] | AO[S][768] (AO doubles as xb).

using u16 = unsigned short;
typedef __bf16 bf16x8 __attribute__((ext_vector_type(8)));
typedef float f32x4 __attribute__((ext_vector_type(4)));
typedef float f32x16 __attribute__((ext_vector_type(16)));
typedef unsigned int u32x4 __attribute__((ext_vector_type(4)));
typedef u16 u16x4 __attribute__((ext_vector_type(4)));

constexpr int SEQ = 4096;
constexpr int DIM = 768;
constexpr int NH = 12;
constexpr int HD = 64;
constexpr int LDT = 72;  // K-tile LDS stride (bf16): 144B rows
constexpr int LDV = 36;  // V-tile LDS stride (bf16): 72B rows (18 dw: conflict-free)
constexpr int LDM = 68;  // merge stride (f32)
constexpr float SM_PRE = 0.18033688011112042f;  // (1/8) * log2(e)
constexpr float DEFER_THR = 8.0f;

__device__ __forceinline__ u16 f2bf(float f) {
  union { float f; unsigned u; } v{f};
  unsigned r = v.u + 0x7fffu + ((v.u >> 16) & 1u);  // RNE
  return (u16)(r >> 16);
}
__device__ __forceinline__ unsigned cvtpk_bf16(float a, float b) {
  unsigned r;
  asm("v_cvt_pk_bf16_f32 %0, %1, %2" : "=v"(r) : "v"(a), "v"(b));
  return r;
}
__device__ __forceinline__ void swap32(unsigned& a, unsigned& b) {
  asm volatile("v_permlane32_swap_b32 %0, %1" : "+v"(a), "+v"(b));
}

// ---------------- prep: fp32 -> bf16 ----------------
__global__ __launch_bounds__(256) void prep_all(const float* __restrict__ x,
                                                const float* __restrict__ wq,
                                                const float* __restrict__ wk,
                                                const float* __restrict__ wv,
                                                u16* __restrict__ xb,
                                                u16* __restrict__ wqb,
                                                u16* __restrict__ wkb,
                                                u16* __restrict__ wvb) {
  constexpr size_t NX = (size_t)SEQ * DIM, NW = (size_t)DIM * DIM;
  size_t i = ((size_t)blockIdx.x * 256 + threadIdx.x) * 8;
  const float* src;
  u16* dst;
  size_t off;
  if (i < NX) { src = x; dst = xb; off = i; }
  else if (i < NX + NW) { src = wq; dst = wqb; off = i - NX; }
  else if (i < NX + 2 * NW) { src = wk; dst = wkb; off = i - NX - 2 * NW + NW; }
  else { src = wv; dst = wvb; off = i - NX - 3 * NW + NW; }
  float4 f0 = *(const float4*)(src + off);
  float4 f1 = *(const float4*)(src + off + 4);
  u32x4 w = {cvtpk_bf16(f0.x, f0.y), cvtpk_bf16(f0.z, f0.w),
             cvtpk_bf16(f1.x, f1.y), cvtpk_bf16(f1.z, f1.w)};
  *(u32x4*)(dst + off) = w;
}

__global__ __launch_bounds__(256) void prep_one(const float* __restrict__ w,
                                                u16* __restrict__ wb) {
  size_t off = ((size_t)blockIdx.x * 256 + threadIdx.x) * 8;
  float4 f0 = *(const float4*)(w + off);
  float4 f1 = *(const float4*)(w + off + 4);
  u32x4 v = {cvtpk_bf16(f0.x, f0.y), cvtpk_bf16(f0.z, f0.w),
             cvtpk_bf16(f1.x, f1.y), cvtpk_bf16(f1.z, f1.w)};
  *(u32x4*)(wb + off) = v;
}

// ---------------- fused QKV GEMM: wave = n-slice of all 3 outputs ----------------
__global__ __launch_bounds__(256) void qkv_gemm(const u16* __restrict__ xb,
                                                const u16* __restrict__ wqb,
                                                const u16* __restrict__ wkb,
                                                const u16* __restrict__ wvb,
                                                const float* __restrict__ bq,
                                                const float* __restrict__ bk,
                                                const float* __restrict__ bv,
                                                u16* __restrict__ Qb,
                                                u16* __restrict__ Kb,
                                                u16* __restrict__ Vtb) {
  __shared__ alignas(16) u16 As[64 * LDT];
  __shared__ alignas(16) u16 Bq[64 * LDT];
  __shared__ alignas(16) u16 Bk[64 * LDT];
  __shared__ alignas(16) u16 Bv[64 * LDT];

  const int tid = threadIdx.x, lane = tid & 63, wave = tid >> 6;
  const int lg = lane >> 4, ln = lane & 15;
  const int bid = blockIdx.x;
  const int swz = (bid & 7) * 96 + (bid >> 3);
  const int mt = swz / 12, nt = swz % 12;
  const int m0 = mt * 64, n0 = nt * 64;
  const int sr = tid >> 2, sc = (tid & 3) * 16;

  f32x4 acc[4][3] = {};  // [m-tile][output]

  for (int kk = 0; kk < DIM; kk += 64) {
    {
      const u32x4* s = (const u32x4*)(xb + (size_t)(m0 + sr) * DIM + kk + sc);
      *(u32x4*)&As[sr * LDT + sc] = s[0];
      *(u32x4*)&As[sr * LDT + sc + 8] = s[1];
    }
    {
      const u32x4* s = (const u32x4*)(wqb + (size_t)(n0 + sr) * DIM + kk + sc);
      *(u32x4*)&Bq[sr * LDT + sc] = s[0];
      *(u32x4*)&Bq[sr * LDT + sc + 8] = s[1];
    }
    {
      const u32x4* s = (const u32x4*)(wkb + (size_t)(n0 + sr) * DIM + kk + sc);
      *(u32x4*)&Bk[sr * LDT + sc] = s[0];
      *(u32x4*)&Bk[sr * LDT + sc + 8] = s[1];
    }
    {
      const u32x4* s = (const u32x4*)(wvb + (size_t)(n0 + sr) * DIM + kk + sc);
      *(u32x4*)&Bv[sr * LDT + sc] = s[0];
      *(u32x4*)&Bv[sr * LDT + sc + 8] = s[1];
    }
    __syncthreads();

#pragma unroll
    for (int c = 0; c < 2; ++c) {
      const int k0 = c * 32 + lg * 8;
      bf16x8 a[4];
#pragma unroll
      for (int i = 0; i < 4; ++i)
        a[i] = __builtin_bit_cast(bf16x8, *(const u32x4*)&As[(i * 16 + ln) * LDT + k0]);
      {
        bf16x8 b = __builtin_bit_cast(bf16x8, *(const u32x4*)&Bq[(wave * 16 + ln) * LDT + k0]);
#pragma unroll
        for (int i = 0; i < 4; ++i)
          acc[i][0] = __builtin_amdgcn_mfma_f32_16x16x32_bf16(a[i], b, acc[i][0], 0, 0, 0);
      }
      {
        bf16x8 b = __builtin_bit_cast(bf16x8, *(const u32x4*)&Bk[(wave * 16 + ln) * LDT + k0]);
#pragma unroll
        for (int i = 0; i < 4; ++i)
          acc[i][1] = __builtin_amdgcn_mfma_f32_16x16x32_bf16(a[i], b, acc[i][1], 0, 0, 0);
      }
      {
        bf16x8 b = __builtin_bit_cast(bf16x8, *(const u32x4*)&Bv[(wave * 16 + ln) * LDT + k0]);
#pragma unroll
        for (int i = 0; i < 4; ++i)
          acc[i][2] = __builtin_amdgcn_mfma_f32_16x16x32_bf16(a[i], b, acc[i][2], 0, 0, 0);
      }
    }
    __syncthreads();
  }

  const int col = n0 + wave * 16 + ln;
  const float bvq = bq[col], bvk = bk[col], bvv = bv[col];
#pragma unroll
  for (int i = 0; i < 4; ++i) {
    const int rowb = m0 + i * 16 + lg * 4;
#pragma unroll
    for (int r = 0; r < 4; ++r) {
      Qb[(size_t)(rowb + r) * DIM + col] = f2bf((acc[i][0][r] + bvq) * SM_PRE);
      Kb[(size_t)(rowb + r) * DIM + col] = f2bf(acc[i][1][r] + bvk);
    }
    u16x4 pk;
#pragma unroll
    for (int r = 0; r < 4; ++r) pk[r] = f2bf(acc[i][2][r] + bvv);
    *(u16x4*)&Vtb[(size_t)col * SEQ + rowb] = pk;
  }
}

// ---------------- out projection (unchanged) ----------------
__global__ __launch_bounds__(256) void out_gemm(const u16* __restrict__ Ab,
                                                const u16* __restrict__ Wb,
                                                const float* __restrict__ bias,
                                                float* __restrict__ out) {
  __shared__ alignas(16) u16 As[64 * LDT];
  __shared__ alignas(16) u16 Bs[64 * LDT];

  const int tid = threadIdx.x, lane = tid & 63, wave = tid >> 6;
  const int lg = lane >> 4, ln = lane & 15;
  const int bid = blockIdx.x;
  const int swz = (bid & 7) * 96 + (bid >> 3);
  const int mt = swz / 12, nt = swz % 12;
  const int m0 = mt * 64, n0 = nt * 64;
  const int sr = tid >> 2, sc = (tid & 3) * 16;

  f32x4 acc[4] = {};

  for (int kk = 0; kk < DIM; kk += 64) {
    {
      const u32x4* s = (const u32x4*)(Ab + (size_t)(m0 + sr) * DIM + kk + sc);
      *(u32x4*)&As[sr * LDT + sc] = s[0];
      *(u32x4*)&As[sr * LDT + sc + 8] = s[1];
    }
    {
      const u32x4* s = (const u32x4*)(Wb + (size_t)(n0 + sr) * DIM + kk + sc);
      *(u32x4*)&Bs[sr * LDT + sc] = s[0];
      *(u32x4*)&Bs[sr * LDT + sc + 8] = s[1];
    }
    __syncthreads();
#pragma unroll
    for (int c = 0; c < 2; ++c) {
      const int k0 = c * 32 + lg * 8;
      bf16x8 a = __builtin_bit_cast(bf16x8, *(const u32x4*)&As[(wave * 16 + ln) * LDT + k0]);
#pragma unroll
      for (int j = 0; j < 4; ++j) {
        bf16x8 b = __builtin_bit_cast(bf16x8, *(const u32x4*)&Bs[(j * 16 + ln) * LDT + k0]);
        acc[j] = __builtin_amdgcn_mfma_f32_16x16x32_bf16(a, b, acc[j], 0, 0, 0);
      }
    }
    __syncthreads();
  }

  const int rowb = m0 + wave * 16 + lg * 4;
#pragma unroll
  for (int j = 0; j < 4; ++j) {
    const int col = n0 + j * 16 + ln;
    const float bv = bias[col];
#pragma unroll
    for (int r = 0; r < 4; ++r) out[(size_t)(rowb + r) * DIM + col] = acc[j][r] + bv;
  }
}

// ---------------- flash attention: 4-way key split, 64 q per wave ----------------
// Grid 768 (64 q-tiles x 12 heads, XCD-swizzled), 4 waves; wave w owns keys
// t*128 + w*32 each round, computes all 64 q (2 column-halves). 4-way merge.
__global__ __launch_bounds__(256, 3) void attn_kernel(const u16* __restrict__ Q,
                                                      const u16* __restrict__ K,
                                                      const u16* __restrict__ Vt,
                                                      u16* __restrict__ AO) {
  __shared__ alignas(16) u16 Ks[4][32 * LDT + 8];  // [parity][key][d]
  __shared__ alignas(16) u16 Vs[4][64 * LDV + 8];  // [parity][d][key]
  __shared__ float sm[4][2][32], sl[4][2][32];

  const int tid = threadIdx.x, lane = tid & 63, wave = tid >> 6;
  const int l31 = lane & 31, hi = lane >> 5;
  const int p = wave;  // key parity
  const int bid = blockIdx.x;
  const int swz = (bid & 7) * 96 + (bid >> 3);  // 768 = 8*96
  const int h = swz >> 6;
  const int q0 = (swz & 63) * 64;

  // Q B-frags: qf[qh][c] -> q col = qh*32+l31, k(d) = c*16 + hi*8 + e
  bf16x8 qf[2][4];
#pragma unroll
  for (int qh = 0; qh < 2; ++qh)
#pragma unroll
    for (int c = 0; c < 4; ++c)
      qf[qh][c] = __builtin_bit_cast(
          bf16x8,
          *(const u32x4*)(Q + (size_t)(q0 + qh * 32 + l31) * DIM + h * HD + c * 16 + hi * 8));

  float m_[2] = {-1e30f, -1e30f}, l_[2] = {0.f, 0.f};
  f32x16 oacc[2][2] = {};  // [qh][nd]: O[q=qh*32+row(r,hi)][d=nd*32+l31]

  // staging: K rows by (tid>>1), V d-rows by (tid>>2)
  const int krow_g = tid >> 1, kpar = krow_g >> 5, klrow = krow_g & 31;
  const int khalf = (tid & 1) * 32;
  const int vd = tid >> 2, vch = tid & 3;

  const u16* Kh = K + (size_t)h * HD;
  const u16* Vh = Vt + (size_t)h * HD * SEQ;
  constexpr int NT = SEQ / 128;  // 32 rounds

  u32x4 kpre[4], vpre[4];
  auto prefetch = [&](int t) {
    const u32x4* s = (const u32x4*)(Kh + (size_t)(t * 128 + krow_g) * DIM + khalf);
    kpre[0] = s[0]; kpre[1] = s[1]; kpre[2] = s[2]; kpre[3] = s[3];
    const u32x4* v = (const u32x4*)(Vh + (size_t)vd * SEQ + t * 128 + vch * 32);
    vpre[0] = v[0]; vpre[1] = v[1]; vpre[2] = v[2]; vpre[3] = v[3];
  };
  prefetch(0);

  for (int t = 0; t < NT; ++t) {
    __syncthreads();  // all waves done reading previous round
    {
      u16* kd = &Ks[kpar][klrow * LDT + khalf];
      *(u32x4*)kd = kpre[0]; *(u32x4*)(kd + 8) = kpre[1];
      *(u32x4*)(kd + 16) = kpre[2]; *(u32x4*)(kd + 24) = kpre[3];
      u16* vp = &Vs[vch][vd * LDV];
      *(u32x4*)vp = vpre[0]; *(u32x4*)(vp + 8) = vpre[1];
      *(u32x4*)(vp + 16) = vpre[2]; *(u32x4*)(vp + 24) = vpre[3];
    }
    __syncthreads();
    prefetch(t + 1 < NT ? t + 1 : t);  // next round, completes under compute

    // S^T = K Q^T on this wave's 32-key tile: col=l31 -> q, row(r,hi) -> key
    f32x16 st[2] = {};
    __builtin_amdgcn_s_setprio(1);
#pragma unroll
    for (int c = 0; c < 4; ++c) {
      bf16x8 kf = __builtin_bit_cast(
          bf16x8, *(const u32x4*)&Ks[p][l31 * LDT + c * 16 + hi * 8]);
      st[0] = __builtin_amdgcn_mfma_f32_32x32x16_bf16(kf, qf[0][c], st[0], 0, 0, 0);
      st[1] = __builtin_amdgcn_mfma_f32_32x32x16_bf16(kf, qf[1][c], st[1], 0, 0, 0);
    }
    __builtin_amdgcn_s_setprio(0);

    // per-qh tile max over the lane's 16 keys + hi-combine
    float pmax[2];
    bool need = false;
#pragma unroll
    for (int qh = 0; qh < 2; ++qh) {
      float x0 = fmaxf(fmaxf(st[qh][0], st[qh][4]), fmaxf(st[qh][8], st[qh][12]));
      float x1 = fmaxf(fmaxf(st[qh][1], st[qh][5]), fmaxf(st[qh][9], st[qh][13]));
      float x2 = fmaxf(fmaxf(st[qh][2], st[qh][6]), fmaxf(st[qh][10], st[qh][14]));
      float x3 = fmaxf(fmaxf(st[qh][3], st[qh][7]), fmaxf(st[qh][11], st[qh][15]));
      float pm = fmaxf(fmaxf(x0, x1), fmaxf(x2, x3));
      pm = fmaxf(pm, __shfl_xor(pm, 32));
      pmax[qh] = pm;
      need = need || (pm > m_[qh] + DEFER_THR);
    }

    if (__ballot(need)) {  // T13: rare after first rounds
#pragma unroll
      for (int qh = 0; qh < 2; ++qh) {
        const float mn = fmaxf(m_[qh], pmax[qh]);
        const float scl = __builtin_amdgcn_exp2f(m_[qh] - mn);
        l_[qh] *= scl;
        m_[qh] = mn;
        float fac[16];
#pragma unroll
        for (int r = 0; r < 16; ++r)
          fac[r] = __shfl(scl, (r & 3) + 8 * (r >> 2) + 4 * hi);
#pragma unroll
        for (int nd = 0; nd < 2; ++nd)
#pragma unroll
          for (int r = 0; r < 16; ++r) oacc[qh][nd][r] *= fac[r];
      }
    }

    // P = exp2(s - m); row-sum
#pragma unroll
    for (int qh = 0; qh < 2; ++qh) {
#pragma unroll
      for (int r = 0; r < 16; ++r) st[qh][r] = __builtin_amdgcn_exp2f(st[qh][r] - m_[qh]);
      float s0 = (st[qh][0] + st[qh][4]) + (st[qh][8] + st[qh][12]);
      float s1 = (st[qh][1] + st[qh][5]) + (st[qh][9] + st[qh][13]);
      float s2 = (st[qh][2] + st[qh][6]) + (st[qh][10] + st[qh][14]);
      float s3 = (st[qh][3] + st[qh][7]) + (st[qh][11] + st[qh][15]);
      float rs = (s0 + s1) + (s2 + s3);
      rs += __shfl_xor(rs, 32);
      l_[qh] += rs;
    }

    // PV A-frags in-register (T12): cvt_pk + permlane32_swap per qh
    bf16x8 pa[2][2];
#pragma unroll
    for (int qh = 0; qh < 2; ++qh) {
      unsigned c0 = cvtpk_bf16(st[qh][0], st[qh][1]), c1 = cvtpk_bf16(st[qh][2], st[qh][3]);
      unsigned c2 = cvtpk_bf16(st[qh][4], st[qh][5]), c3 = cvtpk_bf16(st[qh][6], st[qh][7]);
      unsigned c4 = cvtpk_bf16(st[qh][8], st[qh][9]), c5 = cvtpk_bf16(st[qh][10], st[qh][11]);
      unsigned c6 = cvtpk_bf16(st[qh][12], st[qh][13]), c7 = cvtpk_bf16(st[qh][14], st[qh][15]);
      swap32(c0, c2); swap32(c1, c3); swap32(c4, c6); swap32(c5, c7);
      pa[qh][0] = __builtin_bit_cast(bf16x8, u32x4{c0, c1, c2, c3});  // keys 0-15
      pa[qh][1] = __builtin_bit_cast(bf16x8, u32x4{c4, c5, c6, c7});  // keys 16-31
    }

    // O += P V : V B-frags shared across qh
    __builtin_amdgcn_s_setprio(1);
#pragma unroll
    for (int nd = 0; nd < 2; ++nd) {
      const int vrow = (nd * 32 + l31) * LDV;
      bf16x8 vA = __builtin_bit_cast(bf16x8, *(const u32x4*)&Vs[p][vrow + hi * 8]);
      bf16x8 vB = __builtin_bit_cast(bf16x8, *(const u32x4*)&Vs[p][vrow + 16 + hi * 8]);
      oacc[0][nd] = __builtin_amdgcn_mfma_f32_32x32x16_bf16(pa[0][0], vA, oacc[0][nd], 0, 0, 0);
      oacc[0][nd] = __builtin_amdgcn_mfma_f32_32x32x16_bf16(pa[0][1], vB, oacc[0][nd], 0, 0, 0);
      oacc[1][nd] = __builtin_amdgcn_mfma_f32_32x32x16_bf16(pa[1][0], vA, oacc[1][nd], 0, 0, 0);
      oacc[1][nd] = __builtin_amdgcn_mfma_f32_32x32x16_bf16(pa[1][1], vB, oacc[1][nd], 0, 0, 0);
    }
    __builtin_amdgcn_s_setprio(0);
  }

  // ---- 4-way merge (disjoint key sets): O = sum_w exp2(m_w - M) O_w ----
  if (hi == 0) {
    sm[wave][0][l31] = m_[0]; sm[wave][1][l31] = m_[1];
    sl[wave][0][l31] = l_[0]; sl[wave][1][l31] = l_[1];
  }
  __syncthreads();

  float fac[2], Linv[2];
#pragma unroll
  for (int qh = 0; qh < 2; ++qh) {
    const float a0 = sm[0][qh][l31], a1 = sm[1][qh][l31];
    const float a2 = sm[2][qh][l31], a3 = sm[3][qh][l31];
    const float M = fmaxf(fmaxf(a0, a1), fmaxf(a2, a3));
    const float L = sl[0][qh][l31] * __builtin_amdgcn_exp2f(a0 - M) +
                    sl[1][qh][l31] * __builtin_amdgcn_exp2f(a1 - M) +
                    sl[2][qh][l31] * __builtin_amdgcn_exp2f(a2 - M) +
                    sl[3][qh][l31] * __builtin_amdgcn_exp2f(a3 - M);
    fac[qh] = __builtin_amdgcn_exp2f(m_[qh] - M);
    Linv[qh] = 1.f / L;
  }
  float facr[2][16], Lr[2][16];
#pragma unroll
  for (int qh = 0; qh < 2; ++qh)
#pragma unroll
    for (int r = 0; r < 16; ++r) {
      const int ri = (r & 3) + 8 * (r >> 2) + 4 * hi;
      facr[qh][r] = __shfl(fac[qh], ri);
      Lr[qh][r] = __shfl(Linv[qh], ri);
    }

  float* RA = (float*)&Ks[0][0];  // 64q x LDM f32 = 17408 B (Ks spans 18496)
  float* RB = (float*)&Vs[0][0];
  if (wave == 1 || wave == 3) {
    float* Rg = (wave == 1) ? RA : RB;
#pragma unroll
    for (int qh = 0; qh < 2; ++qh)
#pragma unroll
      for (int nd = 0; nd < 2; ++nd)
#pragma unroll
        for (int r = 0; r < 16; ++r) {
          const int row = qh * 32 + (r & 3) + 8 * (r >> 2) + 4 * hi;
          Rg[row * LDM + nd * 32 + l31] = oacc[qh][nd][r] * facr[qh][r];
        }
  }
  __syncthreads();
  if (wave == 0) {
#pragma unroll
    for (int qh = 0; qh < 2; ++qh)
#pragma unroll
      for (int nd = 0; nd < 2; ++nd)
#pragma unroll
        for (int r = 0; r < 16; ++r) {
          const int row = qh * 32 + (r & 3) + 8 * (r >> 2) + 4 * hi;
          oacc[qh][nd][r] = oacc[qh][nd][r] * facr[qh][r] + RA[row * LDM + nd * 32 + l31];
        }
  } else if (wave == 2) {
#pragma unroll
    for (int qh = 0; qh < 2; ++qh)
#pragma unroll
      for (int nd = 0; nd < 2; ++nd)
#pragma unroll
        for (int r = 0; r < 16; ++r) {
          const int row = qh * 32 + (r & 3) + 8 * (r >> 2) + 4 * hi;
          float* pm = &RB[row * LDM + nd * 32 + l31];
          *pm = oacc[qh][nd][r] * facr[qh][r] + *pm;
        }
  }
  __syncthreads();
  if (wave == 0) {
#pragma unroll
    for (int qh = 0; qh < 2; ++qh)
#pragma unroll
      for (int nd = 0; nd < 2; ++nd)
#pragma unroll
        for (int r = 0; r < 16; ++r) {
          const int row = qh * 32 + (r & 3) + 8 * (r >> 2) + 4 * hi;
          const float v =
              (oacc[qh][nd][r] + RB[row * LDM + nd * 32 + l31]) * Lr[qh][r];
          AO[(size_t)(q0 + row) * DIM + h * HD + nd * 32 + l31] = f2bf(v);
        }
  }
}

extern "C" void kernel_launch(void* const* d_in, const int* in_sizes, int n_in,
                              void* d_out, int out_size, void* d_ws, size_t ws_size,
                              hipStream_t stream) {
  const float* x = (const float*)d_in[0];
  const float* wq = (const float*)d_in[1];
  const float* bq = (const float*)d_in[2];
  const float* wk = (const float*)d_in[3];
  const float* bk = (const float*)d_in[4];
  const float* wv = (const float*)d_in[5];
  const float* bv = (const float*)d_in[6];
  const float* ww = (const float*)d_in[7];
  const float* bw = (const float*)d_in[8];

  const size_t mat = (size_t)SEQ * DIM;
  const size_t nw = (size_t)DIM * DIM;
  if (ws_size < 4 * mat * sizeof(u16)) {
    fprintf(stderr, "kernel_launch: ws too small (%zu)\n", ws_size);
    return;
  }
  u16* Qb = (u16*)d_ws;
  u16* Kb = Qb + mat;
  u16* Vtb = Kb + mat;     // [768][4096]
  u16* AOb = Vtb + mat;    // also xb (sequentially dead)
  u16* xb = AOb;
  u16* wqb = (u16*)d_out;  // d_out as scratch during QKV+attn phases
  u16* wkb = wqb + nw;
  u16* wvb = wkb + nw;
  u16* wwb = Kb;           // K dead after attn

  prep_all<<<dim3(2400), dim3(256), 0, stream>>>(x, wq, wk, wv, xb, wqb, wkb, wvb);
  qkv_gemm<<<dim3(768), dim3(256), 0, stream>>>(xb, wqb, wkb, wvb, bq, bk, bv, Qb, Kb, Vtb);
  attn_kernel<<<dim3(768), dim3(256), 0, stream>>>(Qb, Kb, Vtb, AOb);
  prep_one<<<dim3(288), dim3(256), 0, stream>>>(ww, wwb);
  out_gemm<<<dim3(768), dim3(256), 0, stream>>>(AOb, wwb, bw, (float*)d_out);
}

// Round 7
// 134.808 us; speedup vs baseline: 1.7417x; 1.7417x over previous
//
#include <hip/hip_runtime.h>
#include <cstdio>

// MHA block for MI355X (gfx950). Round 6:
//  - attn: R4 work partition (wave = 32q x 32key-parity, oacc 32 VGPR) +
//    double-buffered K/V LDS with ONE barrier per 64-key round; reads issued
//    before stage-writes; T12 in-reg P, T13 defer-max, T5 setprio.
//  - gemm side: R5 versions (n-slice fused QKV, bf16 preps, out-proj).
// ws (bf16): Q[S][768] | K[S][768] | Vt[768][S] | AO[S][768] (AO doubles as xb).

using u16 = unsigned short;
typedef __bf16 bf16x8 __attribute__((ext_vector_type(8)));
typedef float f32x4 __attribute__((ext_vector_type(4)));
typedef float f32x16 __attribute__((ext_vector_type(16)));
typedef unsigned int u32x4 __attribute__((ext_vector_type(4)));
typedef u16 u16x4 __attribute__((ext_vector_type(4)));

constexpr int SEQ = 4096;
constexpr int DIM = 768;
constexpr int NH = 12;
constexpr int HD = 64;
constexpr int LDT = 72;  // LDS stride (bf16): 144B rows (empirically 0 conflicts)
constexpr int LDM = 68;  // merge stride (f32)
constexpr float SM_PRE = 0.18033688011112042f;  // (1/8) * log2(e)
constexpr float DEFER_THR = 8.0f;

__device__ __forceinline__ u16 f2bf(float f) {
  union { float f; unsigned u; } v{f};
  unsigned r = v.u + 0x7fffu + ((v.u >> 16) & 1u);  // RNE
  return (u16)(r >> 16);
}
__device__ __forceinline__ unsigned cvtpk_bf16(float a, float b) {
  unsigned r;
  asm("v_cvt_pk_bf16_f32 %0, %1, %2" : "=v"(r) : "v"(a), "v"(b));
  return r;
}
__device__ __forceinline__ void swap32(unsigned& a, unsigned& b) {
  asm volatile("v_permlane32_swap_b32 %0, %1" : "+v"(a), "+v"(b));
}
__device__ __forceinline__ bf16x8 bc16(const u16* p) {
  return __builtin_bit_cast(bf16x8, *(const u32x4*)p);
}

// ---------------- prep: fp32 -> bf16 ----------------
__global__ __launch_bounds__(256) void prep_all(const float* __restrict__ x,
                                                const float* __restrict__ wq,
                                                const float* __restrict__ wk,
                                                const float* __restrict__ wv,
                                                u16* __restrict__ xb,
                                                u16* __restrict__ wqb,
                                                u16* __restrict__ wkb,
                                                u16* __restrict__ wvb) {
  constexpr size_t NX = (size_t)SEQ * DIM, NW = (size_t)DIM * DIM;
  size_t i = ((size_t)blockIdx.x * 256 + threadIdx.x) * 8;
  const float* src;
  u16* dst;
  size_t off;
  if (i < NX) { src = x; dst = xb; off = i; }
  else if (i < NX + NW) { src = wq; dst = wqb; off = i - NX; }
  else if (i < NX + 2 * NW) { src = wk; dst = wkb; off = i - NX - 2 * NW + NW; }
  else { src = wv; dst = wvb; off = i - NX - 3 * NW + NW; }
  float4 f0 = *(const float4*)(src + off);
  float4 f1 = *(const float4*)(src + off + 4);
  u32x4 w = {cvtpk_bf16(f0.x, f0.y), cvtpk_bf16(f0.z, f0.w),
             cvtpk_bf16(f1.x, f1.y), cvtpk_bf16(f1.z, f1.w)};
  *(u32x4*)(dst + off) = w;
}

__global__ __launch_bounds__(256) void prep_one(const float* __restrict__ w,
                                                u16* __restrict__ wb) {
  size_t off = ((size_t)blockIdx.x * 256 + threadIdx.x) * 8;
  float4 f0 = *(const float4*)(w + off);
  float4 f1 = *(const float4*)(w + off + 4);
  u32x4 v = {cvtpk_bf16(f0.x, f0.y), cvtpk_bf16(f0.z, f0.w),
             cvtpk_bf16(f1.x, f1.y), cvtpk_bf16(f1.z, f1.w)};
  *(u32x4*)(wb + off) = v;
}

// ---------------- fused QKV GEMM: wave = n-slice of all 3 outputs ----------------
__global__ __launch_bounds__(256) void qkv_gemm(const u16* __restrict__ xb,
                                                const u16* __restrict__ wqb,
                                                const u16* __restrict__ wkb,
                                                const u16* __restrict__ wvb,
                                                const float* __restrict__ bq,
                                                const float* __restrict__ bk,
                                                const float* __restrict__ bv,
                                                u16* __restrict__ Qb,
                                                u16* __restrict__ Kb,
                                                u16* __restrict__ Vtb) {
  __shared__ alignas(16) u16 As[64 * LDT];
  __shared__ alignas(16) u16 Bq[64 * LDT];
  __shared__ alignas(16) u16 Bk[64 * LDT];
  __shared__ alignas(16) u16 Bv[64 * LDT];

  const int tid = threadIdx.x, lane = tid & 63, wave = tid >> 6;
  const int lg = lane >> 4, ln = lane & 15;
  const int bid = blockIdx.x;
  const int swz = (bid & 7) * 96 + (bid >> 3);
  const int mt = swz / 12, nt = swz % 12;
  const int m0 = mt * 64, n0 = nt * 64;
  const int sr = tid >> 2, sc = (tid & 3) * 16;

  f32x4 acc[4][3] = {};  // [m-tile][output]

  for (int kk = 0; kk < DIM; kk += 64) {
    {
      const u32x4* s = (const u32x4*)(xb + (size_t)(m0 + sr) * DIM + kk + sc);
      *(u32x4*)&As[sr * LDT + sc] = s[0];
      *(u32x4*)&As[sr * LDT + sc + 8] = s[1];
    }
    {
      const u32x4* s = (const u32x4*)(wqb + (size_t)(n0 + sr) * DIM + kk + sc);
      *(u32x4*)&Bq[sr * LDT + sc] = s[0];
      *(u32x4*)&Bq[sr * LDT + sc + 8] = s[1];
    }
    {
      const u32x4* s = (const u32x4*)(wkb + (size_t)(n0 + sr) * DIM + kk + sc);
      *(u32x4*)&Bk[sr * LDT + sc] = s[0];
      *(u32x4*)&Bk[sr * LDT + sc + 8] = s[1];
    }
    {
      const u32x4* s = (const u32x4*)(wvb + (size_t)(n0 + sr) * DIM + kk + sc);
      *(u32x4*)&Bv[sr * LDT + sc] = s[0];
      *(u32x4*)&Bv[sr * LDT + sc + 8] = s[1];
    }
    __syncthreads();

#pragma unroll
    for (int c = 0; c < 2; ++c) {
      const int k0 = c * 32 + lg * 8;
      bf16x8 a[4];
#pragma unroll
      for (int i = 0; i < 4; ++i)
        a[i] = bc16(&As[(i * 16 + ln) * LDT + k0]);
      {
        bf16x8 b = bc16(&Bq[(wave * 16 + ln) * LDT + k0]);
#pragma unroll
        for (int i = 0; i < 4; ++i)
          acc[i][0] = __builtin_amdgcn_mfma_f32_16x16x32_bf16(a[i], b, acc[i][0], 0, 0, 0);
      }
      {
        bf16x8 b = bc16(&Bk[(wave * 16 + ln) * LDT + k0]);
#pragma unroll
        for (int i = 0; i < 4; ++i)
          acc[i][1] = __builtin_amdgcn_mfma_f32_16x16x32_bf16(a[i], b, acc[i][1], 0, 0, 0);
      }
      {
        bf16x8 b = bc16(&Bv[(wave * 16 + ln) * LDT + k0]);
#pragma unroll
        for (int i = 0; i < 4; ++i)
          acc[i][2] = __builtin_amdgcn_mfma_f32_16x16x32_bf16(a[i], b, acc[i][2], 0, 0, 0);
      }
    }
    __syncthreads();
  }

  const int col = n0 + wave * 16 + ln;
  const float bvq = bq[col], bvk = bk[col], bvv = bv[col];
#pragma unroll
  for (int i = 0; i < 4; ++i) {
    const int rowb = m0 + i * 16 + lg * 4;
#pragma unroll
    for (int r = 0; r < 4; ++r) {
      Qb[(size_t)(rowb + r) * DIM + col] = f2bf((acc[i][0][r] + bvq) * SM_PRE);
      Kb[(size_t)(rowb + r) * DIM + col] = f2bf(acc[i][1][r] + bvk);
    }
    u16x4 pk;
#pragma unroll
    for (int r = 0; r < 4; ++r) pk[r] = f2bf(acc[i][2][r] + bvv);
    *(u16x4*)&Vtb[(size_t)col * SEQ + rowb] = pk;
  }
}

// ---------------- out projection ----------------
__global__ __launch_bounds__(256) void out_gemm(const u16* __restrict__ Ab,
                                                const u16* __restrict__ Wb,
                                                const float* __restrict__ bias,
                                                float* __restrict__ out) {
  __shared__ alignas(16) u16 As[64 * LDT];
  __shared__ alignas(16) u16 Bs[64 * LDT];

  const int tid = threadIdx.x, lane = tid & 63, wave = tid >> 6;
  const int lg = lane >> 4, ln = lane & 15;
  const int bid = blockIdx.x;
  const int swz = (bid & 7) * 96 + (bid >> 3);
  const int mt = swz / 12, nt = swz % 12;
  const int m0 = mt * 64, n0 = nt * 64;
  const int sr = tid >> 2, sc = (tid & 3) * 16;

  f32x4 acc[4] = {};

  for (int kk = 0; kk < DIM; kk += 64) {
    {
      const u32x4* s = (const u32x4*)(Ab + (size_t)(m0 + sr) * DIM + kk + sc);
      *(u32x4*)&As[sr * LDT + sc] = s[0];
      *(u32x4*)&As[sr * LDT + sc + 8] = s[1];
    }
    {
      const u32x4* s = (const u32x4*)(Wb + (size_t)(n0 + sr) * DIM + kk + sc);
      *(u32x4*)&Bs[sr * LDT + sc] = s[0];
      *(u32x4*)&Bs[sr * LDT + sc + 8] = s[1];
    }
    __syncthreads();
#pragma unroll
    for (int c = 0; c < 2; ++c) {
      const int k0 = c * 32 + lg * 8;
      bf16x8 a = bc16(&As[(wave * 16 + ln) * LDT + k0]);
#pragma unroll
      for (int j = 0; j < 4; ++j) {
        bf16x8 b = bc16(&Bs[(j * 16 + ln) * LDT + k0]);
        acc[j] = __builtin_amdgcn_mfma_f32_16x16x32_bf16(a, b, acc[j], 0, 0, 0);
      }
    }
    __syncthreads();
  }

  const int rowb = m0 + wave * 16 + lg * 4;
#pragma unroll
  for (int j = 0; j < 4; ++j) {
    const int col = n0 + j * 16 + ln;
    const float bv = bias[col];
#pragma unroll
    for (int r = 0; r < 4; ++r) out[(size_t)(rowb + r) * DIM + col] = acc[j][r] + bv;
  }
}

// ---------------- flash attention: dbuf, 1 barrier per 64-key round ----------------
// Grid 768 (64 q-tiles x 12 heads, XCD-swizzled), 4 waves = 2 q-groups x 2
// key-parities. Round = 64 keys; wave (g,p) computes q-rows g*32.., keys p*32..
__global__ __launch_bounds__(256, 3) void attn_kernel(const u16* __restrict__ Q,
                                                      const u16* __restrict__ K,
                                                      const u16* __restrict__ Vt,
                                                      u16* __restrict__ AO) {
  __shared__ alignas(16) u16 Ks[2][64 * LDT];  // [buf][key][d]
  __shared__ alignas(16) u16 Vs[2][64 * LDT];  // [buf][d][key]
  __shared__ float sm[4][32], sl[4][32];

  const int tid = threadIdx.x, lane = tid & 63, wave = tid >> 6;
  const int l31 = lane & 31, hi = lane >> 5;
  const int g = wave >> 1, p = wave & 1;
  const int bid = blockIdx.x;
  const int swz = (bid & 7) * 96 + (bid >> 3);  // 768 = 8*96
  const int h = swz >> 6;
  const int q0 = (swz & 63) * 64;
  const int qw = q0 + g * 32;

  // Q B-frags: q col = l31, k(d) = c*16 + hi*8 + e
  bf16x8 qf[4];
#pragma unroll
  for (int c = 0; c < 4; ++c)
    qf[c] = bc16(Q + (size_t)(qw + l31) * DIM + h * HD + c * 16 + hi * 8);

  float m_ = -1e30f, l_ = 0.f;
  f32x16 oacc[2] = {};  // [nd]: O[q=(r&3)+8*(r>>2)+4*hi][d=nd*32+l31]

  // staging: thread -> 32B of K row (srow) + 32B of V row (srow)
  const int srow = tid >> 2;
  const int scol = (tid & 3) * 16;

  const u16* Kh = K + (size_t)h * HD;
  const u16* Vh = Vt + (size_t)h * HD * SEQ;
  constexpr int NT = SEQ / 64;  // 64 rounds

  u32x4 kp0, kp1, vp0, vp1;
  auto pf = [&](int t) {
    const u32x4* s = (const u32x4*)(Kh + (size_t)(t * 64 + srow) * DIM + scol);
    kp0 = s[0]; kp1 = s[1];
    const u32x4* v = (const u32x4*)(Vh + (size_t)srow * SEQ + t * 64 + scol);
    vp0 = v[0]; vp1 = v[1];
  };
  auto stage = [&](int buf) {
    u16* kd = &Ks[buf][srow * LDT + scol];
    *(u32x4*)kd = kp0; *(u32x4*)(kd + 8) = kp1;
    u16* vd = &Vs[buf][srow * LDT + scol];
    *(u32x4*)vd = vp0; *(u32x4*)(vd + 8) = vp1;
  };

  pf(0);
  stage(0);
  pf(1);
  __syncthreads();

  auto round = [&](int t, int cur) {
    // preload this round's K-frags (reads issued before stage writes; DS in-order)
    bf16x8 kf[4];
#pragma unroll
    for (int c = 0; c < 4; ++c)
      kf[c] = bc16(&Ks[cur][(p * 32 + l31) * LDT + c * 16 + hi * 8]);

    // stage next round into other buffer (regs prefetched last round), then
    // issue the round-after global loads; both overlap this round's compute.
    if (t + 1 < NT) {
      stage(cur ^ 1);
      pf(t + 2 < NT ? t + 2 : t + 1);
    }

    // S^T = K Q^T : col=l31 -> q, row(reg,hi) -> key = p*32 + (r&3)+8*(r>>2)+4*hi
    f32x16 st = {};
    __builtin_amdgcn_s_setprio(1);
#pragma unroll
    for (int c = 0; c < 4; ++c)
      st = __builtin_amdgcn_mfma_f32_32x32x16_bf16(kf[c], qf[c], st, 0, 0, 0);
    __builtin_amdgcn_s_setprio(0);

    // tile max over lane's 16 values + hi-combine
    float x0 = fmaxf(fmaxf(st[0], st[4]), fmaxf(st[8], st[12]));
    float x1 = fmaxf(fmaxf(st[1], st[5]), fmaxf(st[9], st[13]));
    float x2 = fmaxf(fmaxf(st[2], st[6]), fmaxf(st[10], st[14]));
    float x3 = fmaxf(fmaxf(st[3], st[7]), fmaxf(st[11], st[15]));
    float pm = fmaxf(fmaxf(x0, x1), fmaxf(x2, x3));
    pm = fmaxf(pm, __shfl_xor(pm, 32));

    if (__ballot(pm > m_ + DEFER_THR)) {  // T13: rare after first rounds
      const float mn = fmaxf(m_, pm);
      const float scl = __builtin_amdgcn_exp2f(m_ - mn);
      l_ *= scl;
      m_ = mn;
      float fac[16];
#pragma unroll
      for (int r = 0; r < 16; ++r)
        fac[r] = __shfl(scl, (r & 3) + 8 * (r >> 2) + 4 * hi);
#pragma unroll
      for (int nd = 0; nd < 2; ++nd)
#pragma unroll
        for (int r = 0; r < 16; ++r) oacc[nd][r] *= fac[r];
    }

    // P = exp2(s - m); row-sum
#pragma unroll
    for (int r = 0; r < 16; ++r) st[r] = __builtin_amdgcn_exp2f(st[r] - m_);
    {
      float s0 = (st[0] + st[4]) + (st[8] + st[12]);
      float s1 = (st[1] + st[5]) + (st[9] + st[13]);
      float s2 = (st[2] + st[6]) + (st[10] + st[14]);
      float s3 = (st[3] + st[7]) + (st[11] + st[15]);
      float rs = (s0 + s1) + (s2 + s3);
      rs += __shfl_xor(rs, 32);
      l_ += rs;
    }

    // PV A-frags in-register (T12)
    unsigned c0 = cvtpk_bf16(st[0], st[1]), c1 = cvtpk_bf16(st[2], st[3]);
    unsigned c2 = cvtpk_bf16(st[4], st[5]), c3 = cvtpk_bf16(st[6], st[7]);
    unsigned c4 = cvtpk_bf16(st[8], st[9]), c5 = cvtpk_bf16(st[10], st[11]);
    unsigned c6 = cvtpk_bf16(st[12], st[13]), c7 = cvtpk_bf16(st[14], st[15]);
    swap32(c0, c2); swap32(c1, c3); swap32(c4, c6); swap32(c5, c7);
    bf16x8 pa0 = __builtin_bit_cast(bf16x8, u32x4{c0, c1, c2, c3});  // keys 0-15
    bf16x8 pa1 = __builtin_bit_cast(bf16x8, u32x4{c4, c5, c6, c7});  // keys 16-31

    // O += P V (reads of buf[cur]; queued after stage writes, long drained)
    __builtin_amdgcn_s_setprio(1);
#pragma unroll
    for (int nd = 0; nd < 2; ++nd) {
      const int vrow = (nd * 32 + l31) * LDT + p * 32;
      bf16x8 vA = bc16(&Vs[cur][vrow + hi * 8]);
      oacc[nd] = __builtin_amdgcn_mfma_f32_32x32x16_bf16(pa0, vA, oacc[nd], 0, 0, 0);
      bf16x8 vB = bc16(&Vs[cur][vrow + 16 + hi * 8]);
      oacc[nd] = __builtin_amdgcn_mfma_f32_32x32x16_bf16(pa1, vB, oacc[nd], 0, 0, 0);
    }
    __builtin_amdgcn_s_setprio(0);
    __syncthreads();  // single rendezvous per round
  };

  for (int t = 0; t < NT; t += 2) {
    round(t, 0);
    round(t + 1, 1);
  }

  // ---- merge parity partners (g,0) + (g,1) ----
  if (hi == 0) { sm[wave][l31] = m_; sl[wave][l31] = l_; }
  __syncthreads();

  const float m0s = sm[g * 2][l31], m1s = sm[g * 2 + 1][l31];
  const float l0s = sl[g * 2][l31], l1s = sl[g * 2 + 1][l31];
  const float M = fmaxf(m0s, m1s);
  const float L = l0s * __builtin_amdgcn_exp2f(m0s - M) +
                  l1s * __builtin_amdgcn_exp2f(m1s - M);
  const float fac = __builtin_amdgcn_exp2f(m_ - M);
  const float Linv = 1.f / L;
  float facr[16], Lr[16];
#pragma unroll
  for (int r = 0; r < 16; ++r) {
    const int ri = (r & 3) + 8 * (r >> 2) + 4 * hi;
    facr[r] = __shfl(fac, ri);
    Lr[r] = __shfl(Linv, ri);
  }

  float* Om = (float*)Ks;  // overlay: 64 x LDM f32 = 17408 B (Ks spans 18432)
  if (p == 1) {
#pragma unroll
    for (int nd = 0; nd < 2; ++nd)
#pragma unroll
      for (int r = 0; r < 16; ++r) {
        const int row = (r & 3) + 8 * (r >> 2) + 4 * hi;
        Om[(g * 32 + row) * LDM + nd * 32 + l31] = oacc[nd][r] * facr[r];
      }
  }
  __syncthreads();
  if (p == 0) {
#pragma unroll
    for (int nd = 0; nd < 2; ++nd)
#pragma unroll
      for (int r = 0; r < 16; ++r) {
        const int row = (r & 3) + 8 * (r >> 2) + 4 * hi;
        const float v = (oacc[nd][r] * facr[r] +
                         Om[(g * 32 + row) * LDM + nd * 32 + l31]) * Lr[r];
        AO[(size_t)(qw + row) * DIM + h * HD + nd * 32 + l31] = f2bf(v);
      }
  }
}

extern "C" void kernel_launch(void* const* d_in, const int* in_sizes, int n_in,
                              void* d_out, int out_size, void* d_ws, size_t ws_size,
                              hipStream_t stream) {
  const float* x = (const float*)d_in[0];
  const float* wq = (const float*)d_in[1];
  const float* bq = (const float*)d_in[2];
  const float* wk = (const float*)d_in[3];
  const float* bk = (const float*)d_in[4];
  const float* wv = (const float*)d_in[5];
  const float* bv = (const float*)d_in[6];
  const float* ww = (const float*)d_in[7];
  const float* bw = (const float*)d_in[8];

  const size_t mat = (size_t)SEQ * DIM;
  const size_t nw = (size_t)DIM * DIM;
  if (ws_size < 4 * mat * sizeof(u16)) {
    fprintf(stderr, "kernel_launch: ws too small (%zu)\n", ws_size);
    return;
  }
  u16* Qb = (u16*)d_ws;
  u16* Kb = Qb + mat;
  u16* Vtb = Kb + mat;     // [768][4096]
  u16* AOb = Vtb + mat;    // also xb (sequentially dead)
  u16* xb = AOb;
  u16* wqb = (u16*)d_out;  // d_out as scratch during QKV+attn phases
  u16* wkb = wqb + nw;
  u16* wvb = wkb + nw;
  u16* wwb = Kb;           // K dead after attn

  prep_all<<<dim3(2400), dim3(256), 0, stream>>>(x, wq, wk, wv, xb, wqb, wkb, wvb);
  qkv_gemm<<<dim3(768), dim3(256), 0, stream>>>(xb, wqb, wkb, wvb, bq, bk, bv, Qb, Kb, Vtb);
  attn_kernel<<<dim3(768), dim3(256), 0, stream>>>(Qb, Kb, Vtb, AOb);
  prep_one<<<dim3(288), dim3(256), 0, stream>>>(ww, wwb);
  out_gemm<<<dim3(768), dim3(256), 0, stream>>>(AOb, wwb, bw, (float*)d_out);
}

// Round 8
// 131.453 us; speedup vs baseline: 1.7861x; 1.0255x over previous
//
#include <hip/hip_runtime.h>
#include <cstdio>

// MHA block for MI355X (gfx950). Round 7:
//  - attn: R6 structure + V-frag preload before staging writes (staging off
//    the PV critical path), max3-shaped max tree.
//  - gemm: double-buffered LDS, BK=32, one barrier per K-step.
// ws (bf16): Q[S][768] | K[S][768] | Vt[768][S] | AO[S][768] (AO doubles as xb).

using u16 = unsigned short;
typedef __bf16 bf16x8 __attribute__((ext_vector_type(8)));
typedef float f32x4 __attribute__((ext_vector_type(4)));
typedef float f32x16 __attribute__((ext_vector_type(16)));
typedef unsigned int u32x4 __attribute__((ext_vector_type(4)));
typedef u16 u16x4 __attribute__((ext_vector_type(4)));

constexpr int SEQ = 4096;
constexpr int DIM = 768;
constexpr int NH = 12;
constexpr int HD = 64;
constexpr int LDT = 72;   // attn LDS stride (bf16): 144B rows
constexpr int LDA2 = 40;  // gemm LDS stride (bf16): 32 + 8 pad
constexpr int LDM = 68;   // merge stride (f32)
constexpr float SM_PRE = 0.18033688011112042f;  // (1/8) * log2(e)
constexpr float DEFER_THR = 8.0f;

__device__ __forceinline__ u16 f2bf(float f) {
  union { float f; unsigned u; } v{f};
  unsigned r = v.u + 0x7fffu + ((v.u >> 16) & 1u);  // RNE
  return (u16)(r >> 16);
}
__device__ __forceinline__ unsigned cvtpk_bf16(float a, float b) {
  unsigned r;
  asm("v_cvt_pk_bf16_f32 %0, %1, %2" : "=v"(r) : "v"(a), "v"(b));
  return r;
}
__device__ __forceinline__ void swap32(unsigned& a, unsigned& b) {
  asm volatile("v_permlane32_swap_b32 %0, %1" : "+v"(a), "+v"(b));
}
__device__ __forceinline__ bf16x8 bc16(const u16* p) {
  return __builtin_bit_cast(bf16x8, *(const u32x4*)p);
}
__device__ __forceinline__ float fmax3(float a, float b, float c) {
  return fmaxf(fmaxf(a, b), c);  // clang fuses to v_max3_f32
}

// ---------------- prep: fp32 -> bf16 ----------------
__global__ __launch_bounds__(256) void prep_all(const float* __restrict__ x,
                                                const float* __restrict__ wq,
                                                const float* __restrict__ wk,
                                                const float* __restrict__ wv,
                                                u16* __restrict__ xb,
                                                u16* __restrict__ wqb,
                                                u16* __restrict__ wkb,
                                                u16* __restrict__ wvb) {
  constexpr size_t NX = (size_t)SEQ * DIM, NW = (size_t)DIM * DIM;
  size_t i = ((size_t)blockIdx.x * 256 + threadIdx.x) * 8;
  const float* src;
  u16* dst;
  size_t off;
  if (i < NX) { src = x; dst = xb; off = i; }
  else if (i < NX + NW) { src = wq; dst = wqb; off = i - NX; }
  else if (i < NX + 2 * NW) { src = wk; dst = wkb; off = i - NX - 2 * NW + NW; }
  else { src = wv; dst = wvb; off = i - NX - 3 * NW + NW; }
  float4 f0 = *(const float4*)(src + off);
  float4 f1 = *(const float4*)(src + off + 4);
  u32x4 w = {cvtpk_bf16(f0.x, f0.y), cvtpk_bf16(f0.z, f0.w),
             cvtpk_bf16(f1.x, f1.y), cvtpk_bf16(f1.z, f1.w)};
  *(u32x4*)(dst + off) = w;
}

__global__ __launch_bounds__(256) void prep_one(const float* __restrict__ w,
                                                u16* __restrict__ wb) {
  size_t off = ((size_t)blockIdx.x * 256 + threadIdx.x) * 8;
  float4 f0 = *(const float4*)(w + off);
  float4 f1 = *(const float4*)(w + off + 4);
  u32x4 v = {cvtpk_bf16(f0.x, f0.y), cvtpk_bf16(f0.z, f0.w),
             cvtpk_bf16(f1.x, f1.y), cvtpk_bf16(f1.z, f1.w)};
  *(u32x4*)(wb + off) = v;
}

// ---------------- fused QKV GEMM: dbuf, BK=32, 1 barrier/step ----------------
__global__ __launch_bounds__(256) void qkv_gemm(const u16* __restrict__ xb,
                                                const u16* __restrict__ wqb,
                                                const u16* __restrict__ wkb,
                                                const u16* __restrict__ wvb,
                                                const float* __restrict__ bq,
                                                const float* __restrict__ bk,
                                                const float* __restrict__ bv,
                                                u16* __restrict__ Qb,
                                                u16* __restrict__ Kb,
                                                u16* __restrict__ Vtb) {
  __shared__ alignas(16) u16 As[2][64 * LDA2];
  __shared__ alignas(16) u16 Bq[2][64 * LDA2];
  __shared__ alignas(16) u16 Bk[2][64 * LDA2];
  __shared__ alignas(16) u16 Bv[2][64 * LDA2];

  const int tid = threadIdx.x, lane = tid & 63, wave = tid >> 6;
  const int lg = lane >> 4, ln = lane & 15;
  const int bid = blockIdx.x;
  const int swz = (bid & 7) * 96 + (bid >> 3);
  const int mt = swz / 12, nt = swz % 12;
  const int m0 = mt * 64, n0 = nt * 64;
  const int srow = tid >> 2, scol = (tid & 3) * 8;

  f32x4 acc[4][3] = {};  // [m-tile][output]

  u32x4 pA, pQ, pK, pV;
  auto pf = [&](int kk) {
    pA = *(const u32x4*)(xb + (size_t)(m0 + srow) * DIM + kk + scol);
    pQ = *(const u32x4*)(wqb + (size_t)(n0 + srow) * DIM + kk + scol);
    pK = *(const u32x4*)(wkb + (size_t)(n0 + srow) * DIM + kk + scol);
    pV = *(const u32x4*)(wvb + (size_t)(n0 + srow) * DIM + kk + scol);
  };
  auto stage = [&](int b) {
    *(u32x4*)&As[b][srow * LDA2 + scol] = pA;
    *(u32x4*)&Bq[b][srow * LDA2 + scol] = pQ;
    *(u32x4*)&Bk[b][srow * LDA2 + scol] = pK;
    *(u32x4*)&Bv[b][srow * LDA2 + scol] = pV;
  };

  constexpr int NS = DIM / 32;  // 24
  pf(0);
  stage(0);
  pf(32);
  __syncthreads();

  for (int s = 0; s < NS; ++s) {
    const int cur = s & 1;
    // frag reads (issue first)
    bf16x8 a[4];
#pragma unroll
    for (int i = 0; i < 4; ++i)
      a[i] = bc16(&As[cur][(i * 16 + ln) * LDA2 + lg * 8]);
    bf16x8 fq = bc16(&Bq[cur][(wave * 16 + ln) * LDA2 + lg * 8]);
    bf16x8 fk = bc16(&Bk[cur][(wave * 16 + ln) * LDA2 + lg * 8]);
    bf16x8 fv = bc16(&Bv[cur][(wave * 16 + ln) * LDA2 + lg * 8]);
    // stage next from regs, prefetch next-next (overlap MFMA)
    if (s + 1 < NS) {
      stage(cur ^ 1);
      if (s + 2 < NS) pf((s + 2) * 32);
    }
#pragma unroll
    for (int i = 0; i < 4; ++i) {
      acc[i][0] = __builtin_amdgcn_mfma_f32_16x16x32_bf16(a[i], fq, acc[i][0], 0, 0, 0);
      acc[i][1] = __builtin_amdgcn_mfma_f32_16x16x32_bf16(a[i], fk, acc[i][1], 0, 0, 0);
      acc[i][2] = __builtin_amdgcn_mfma_f32_16x16x32_bf16(a[i], fv, acc[i][2], 0, 0, 0);
    }
    __syncthreads();
  }

  const int col = n0 + wave * 16 + ln;
  const float bvq = bq[col], bvk = bk[col], bvv = bv[col];
#pragma unroll
  for (int i = 0; i < 4; ++i) {
    const int rowb = m0 + i * 16 + lg * 4;
#pragma unroll
    for (int r = 0; r < 4; ++r) {
      Qb[(size_t)(rowb + r) * DIM + col] = f2bf((acc[i][0][r] + bvq) * SM_PRE);
      Kb[(size_t)(rowb + r) * DIM + col] = f2bf(acc[i][1][r] + bvk);
    }
    u16x4 pk;
#pragma unroll
    for (int r = 0; r < 4; ++r) pk[r] = f2bf(acc[i][2][r] + bvv);
    *(u16x4*)&Vtb[(size_t)col * SEQ + rowb] = pk;
  }
}

// ---------------- out projection: dbuf, BK=32 ----------------
__global__ __launch_bounds__(256) void out_gemm(const u16* __restrict__ Ab,
                                                const u16* __restrict__ Wb,
                                                const float* __restrict__ bias,
                                                float* __restrict__ out) {
  __shared__ alignas(16) u16 As[2][64 * LDA2];
  __shared__ alignas(16) u16 Bs[2][64 * LDA2];

  const int tid = threadIdx.x, lane = tid & 63, wave = tid >> 6;
  const int lg = lane >> 4, ln = lane & 15;
  const int bid = blockIdx.x;
  const int swz = (bid & 7) * 96 + (bid >> 3);
  const int mt = swz / 12, nt = swz % 12;
  const int m0 = mt * 64, n0 = nt * 64;
  const int srow = tid >> 2, scol = (tid & 3) * 8;

  f32x4 acc[4] = {};

  u32x4 pA, pB;
  auto pf = [&](int kk) {
    pA = *(const u32x4*)(Ab + (size_t)(m0 + srow) * DIM + kk + scol);
    pB = *(const u32x4*)(Wb + (size_t)(n0 + srow) * DIM + kk + scol);
  };
  auto stage = [&](int b) {
    *(u32x4*)&As[b][srow * LDA2 + scol] = pA;
    *(u32x4*)&Bs[b][srow * LDA2 + scol] = pB;
  };

  constexpr int NS = DIM / 32;
  pf(0);
  stage(0);
  pf(32);
  __syncthreads();

  for (int s = 0; s < NS; ++s) {
    const int cur = s & 1;
    bf16x8 b = bc16(&Bs[cur][(wave * 16 + ln) * LDA2 + lg * 8]);
    bf16x8 a[4];
#pragma unroll
    for (int j = 0; j < 4; ++j)
      a[j] = bc16(&As[cur][(j * 16 + ln) * LDA2 + lg * 8]);
    if (s + 1 < NS) {
      stage(cur ^ 1);
      if (s + 2 < NS) pf((s + 2) * 32);
    }
#pragma unroll
    for (int j = 0; j < 4; ++j)
      acc[j] = __builtin_amdgcn_mfma_f32_16x16x32_bf16(a[j], b, acc[j], 0, 0, 0);
    __syncthreads();
  }

  // C row = j*16+lg*4+r (m), col = wave*16+ln (n)
  const int col = n0 + wave * 16 + ln;
  const float bv = bias[col];
#pragma unroll
  for (int j = 0; j < 4; ++j) {
    const int rowb = m0 + j * 16 + lg * 4;
#pragma unroll
    for (int r = 0; r < 4; ++r) out[(size_t)(rowb + r) * DIM + col] = acc[j][r] + bv;
  }
}

// ---------------- flash attention: dbuf, V-preload, 1 barrier/round ----------------
// Grid 768 (64 q-tiles x 12 heads, XCD-swizzled), 4 waves = 2 q-groups x 2
// key-parities. Round = 64 keys; wave (g,p) computes q-rows g*32.., keys p*32..
__global__ __launch_bounds__(256, 3) void attn_kernel(const u16* __restrict__ Q,
                                                      const u16* __restrict__ K,
                                                      const u16* __restrict__ Vt,
                                                      u16* __restrict__ AO) {
  __shared__ alignas(16) u16 Ks[2][64 * LDT];  // [buf][key][d]
  __shared__ alignas(16) u16 Vs[2][64 * LDT];  // [buf][d][key]
  __shared__ float sm[4][32], sl[4][32];

  const int tid = threadIdx.x, lane = tid & 63, wave = tid >> 6;
  const int l31 = lane & 31, hi = lane >> 5;
  const int g = wave >> 1, p = wave & 1;
  const int bid = blockIdx.x;
  const int swz = (bid & 7) * 96 + (bid >> 3);  // 768 = 8*96
  const int h = swz >> 6;
  const int q0 = (swz & 63) * 64;
  const int qw = q0 + g * 32;

  // Q B-frags: q col = l31, k(d) = c*16 + hi*8 + e
  bf16x8 qf[4];
#pragma unroll
  for (int c = 0; c < 4; ++c)
    qf[c] = bc16(Q + (size_t)(qw + l31) * DIM + h * HD + c * 16 + hi * 8);

  float m_ = -1e30f, l_ = 0.f;
  f32x16 oacc[2] = {};  // [nd]: O[q=(r&3)+8*(r>>2)+4*hi][d=nd*32+l31]

  const int srow = tid >> 2;
  const int scol = (tid & 3) * 16;

  const u16* Kh = K + (size_t)h * HD;
  const u16* Vh = Vt + (size_t)h * HD * SEQ;
  constexpr int NT = SEQ / 64;  // 64 rounds

  u32x4 kp0, kp1, vp0, vp1;
  auto pf = [&](int t) {
    const u32x4* s = (const u32x4*)(Kh + (size_t)(t * 64 + srow) * DIM + scol);
    kp0 = s[0]; kp1 = s[1];
    const u32x4* v = (const u32x4*)(Vh + (size_t)srow * SEQ + t * 64 + scol);
    vp0 = v[0]; vp1 = v[1];
  };
  auto stage = [&](int buf) {
    u16* kd = &Ks[buf][srow * LDT + scol];
    *(u32x4*)kd = kp0; *(u32x4*)(kd + 8) = kp1;
    u16* vd = &Vs[buf][srow * LDT + scol];
    *(u32x4*)vd = vp0; *(u32x4*)(vd + 8) = vp1;
  };

  pf(0);
  stage(0);
  pf(1);
  __syncthreads();

  auto round = [&](int t, int cur) {
    // preload this round's K AND V frags before any staging writes, so the
    // in-order DS queue never puts stage-writes on the MFMA critical paths.
    bf16x8 kf0 = bc16(&Ks[cur][(p * 32 + l31) * LDT + 0 * 16 + hi * 8]);
    bf16x8 kf1 = bc16(&Ks[cur][(p * 32 + l31) * LDT + 1 * 16 + hi * 8]);
    bf16x8 kf2 = bc16(&Ks[cur][(p * 32 + l31) * LDT + 2 * 16 + hi * 8]);
    bf16x8 kf3 = bc16(&Ks[cur][(p * 32 + l31) * LDT + 3 * 16 + hi * 8]);
    const int vr0 = (0 * 32 + l31) * LDT + p * 32;
    const int vr1 = (1 * 32 + l31) * LDT + p * 32;
    bf16x8 vf00 = bc16(&Vs[cur][vr0 + hi * 8]);
    bf16x8 vf01 = bc16(&Vs[cur][vr0 + 16 + hi * 8]);
    bf16x8 vf10 = bc16(&Vs[cur][vr1 + hi * 8]);
    bf16x8 vf11 = bc16(&Vs[cur][vr1 + 16 + hi * 8]);

    // stage next round into other buffer; issue round-after global loads.
    if (t + 1 < NT) {
      stage(cur ^ 1);
      pf(t + 2 < NT ? t + 2 : t + 1);
    }

    // S^T = K Q^T
    f32x16 st = {};
    __builtin_amdgcn_s_setprio(1);
    st = __builtin_amdgcn_mfma_f32_32x32x16_bf16(kf0, qf[0], st, 0, 0, 0);
    st = __builtin_amdgcn_mfma_f32_32x32x16_bf16(kf1, qf[1], st, 0, 0, 0);
    st = __builtin_amdgcn_mfma_f32_32x32x16_bf16(kf2, qf[2], st, 0, 0, 0);
    st = __builtin_amdgcn_mfma_f32_32x32x16_bf16(kf3, qf[3], st, 0, 0, 0);
    __builtin_amdgcn_s_setprio(0);

    // tile max (max3 tree) + hi-combine
    float g0 = fmax3(st[0], st[4], st[8]);
    float g1 = fmax3(st[12], st[1], st[5]);
    float g2 = fmax3(st[9], st[13], st[2]);
    float g3 = fmax3(st[6], st[10], st[14]);
    float g4 = fmax3(st[3], st[7], st[11]);
    float pm = fmaxf(fmax3(g0, g1, g2), fmax3(g3, g4, st[15]));
    pm = fmaxf(pm, __shfl_xor(pm, 32));

    if (__ballot(pm > m_ + DEFER_THR)) {  // T13: rare after first rounds
      const float mn = fmaxf(m_, pm);
      const float scl = __builtin_amdgcn_exp2f(m_ - mn);
      l_ *= scl;
      m_ = mn;
      float fac[16];
#pragma unroll
      for (int r = 0; r < 16; ++r)
        fac[r] = __shfl(scl, (r & 3) + 8 * (r >> 2) + 4 * hi);
#pragma unroll
      for (int nd = 0; nd < 2; ++nd)
#pragma unroll
        for (int r = 0; r < 16; ++r) oacc[nd][r] *= fac[r];
    }

    // P = exp2(s - m); row-sum
#pragma unroll
    for (int r = 0; r < 16; ++r) st[r] = __builtin_amdgcn_exp2f(st[r] - m_);
    {
      float s0 = (st[0] + st[4]) + (st[8] + st[12]);
      float s1 = (st[1] + st[5]) + (st[9] + st[13]);
      float s2 = (st[2] + st[6]) + (st[10] + st[14]);
      float s3 = (st[3] + st[7]) + (st[11] + st[15]);
      float rs = (s0 + s1) + (s2 + s3);
      rs += __shfl_xor(rs, 32);
      l_ += rs;
    }

    // PV A-frags in-register (T12)
    unsigned c0 = cvtpk_bf16(st[0], st[1]), c1 = cvtpk_bf16(st[2], st[3]);
    unsigned c2 = cvtpk_bf16(st[4], st[5]), c3 = cvtpk_bf16(st[6], st[7]);
    unsigned c4 = cvtpk_bf16(st[8], st[9]), c5 = cvtpk_bf16(st[10], st[11]);
    unsigned c6 = cvtpk_bf16(st[12], st[13]), c7 = cvtpk_bf16(st[14], st[15]);
    swap32(c0, c2); swap32(c1, c3); swap32(c4, c6); swap32(c5, c7);
    bf16x8 pa0 = __builtin_bit_cast(bf16x8, u32x4{c0, c1, c2, c3});  // keys 0-15
    bf16x8 pa1 = __builtin_bit_cast(bf16x8, u32x4{c4, c5, c6, c7});  // keys 16-31

    // O += P V (vf preloaded; no LDS dependency here)
    __builtin_amdgcn_s_setprio(1);
    oacc[0] = __builtin_amdgcn_mfma_f32_32x32x16_bf16(pa0, vf00, oacc[0], 0, 0, 0);
    oacc[0] = __builtin_amdgcn_mfma_f32_32x32x16_bf16(pa1, vf01, oacc[0], 0, 0, 0);
    oacc[1] = __builtin_amdgcn_mfma_f32_32x32x16_bf16(pa0, vf10, oacc[1], 0, 0, 0);
    oacc[1] = __builtin_amdgcn_mfma_f32_32x32x16_bf16(pa1, vf11, oacc[1], 0, 0, 0);
    __builtin_amdgcn_s_setprio(0);
    __syncthreads();  // single rendezvous per round
  };

  for (int t = 0; t < NT; t += 2) {
    round(t, 0);
    round(t + 1, 1);
  }

  // ---- merge parity partners (g,0) + (g,1) ----
  if (hi == 0) { sm[wave][l31] = m_; sl[wave][l31] = l_; }
  __syncthreads();

  const float m0s = sm[g * 2][l31], m1s = sm[g * 2 + 1][l31];
  const float l0s = sl[g * 2][l31], l1s = sl[g * 2 + 1][l31];
  const float M = fmaxf(m0s, m1s);
  const float L = l0s * __builtin_amdgcn_exp2f(m0s - M) +
                  l1s * __builtin_amdgcn_exp2f(m1s - M);
  const float fac = __builtin_amdgcn_exp2f(m_ - M);
  const float Linv = 1.f / L;
  float facr[16], Lr[16];
#pragma unroll
  for (int r = 0; r < 16; ++r) {
    const int ri = (r & 3) + 8 * (r >> 2) + 4 * hi;
    facr[r] = __shfl(fac, ri);
    Lr[r] = __shfl(Linv, ri);
  }

  float* Om = (float*)Ks;  // overlay: 64 x LDM f32 = 17408 B (Ks spans 18432)
  if (p == 1) {
#pragma unroll
    for (int nd = 0; nd < 2; ++nd)
#pragma unroll
      for (int r = 0; r < 16; ++r) {
        const int row = (r & 3) + 8 * (r >> 2) + 4 * hi;
        Om[(g * 32 + row) * LDM + nd * 32 + l31] = oacc[nd][r] * facr[r];
      }
  }
  __syncthreads();
  if (p == 0) {
#pragma unroll
    for (int nd = 0; nd < 2; ++nd)
#pragma unroll
      for (int r = 0; r < 16; ++r) {
        const int row = (r & 3) + 8 * (r >> 2) + 4 * hi;
        const float v = (oacc[nd][r] * facr[r] +
                         Om[(g * 32 + row) * LDM + nd * 32 + l31]) * Lr[r];
        AO[(size_t)(qw + row) * DIM + h * HD + nd * 32 + l31] = f2bf(v);
      }
  }
}

extern "C" void kernel_launch(void* const* d_in, const int* in_sizes, int n_in,
                              void* d_out, int out_size, void* d_ws, size_t ws_size,
                              hipStream_t stream) {
  const float* x = (const float*)d_in[0];
  const float* wq = (const float*)d_in[1];
  const float* bq = (const float*)d_in[2];
  const float* wk = (const float*)d_in[3];
  const float* bk = (const float*)d_in[4];
  const float* wv = (const float*)d_in[5];
  const float* bv = (const float*)d_in[6];
  const float* ww = (const float*)d_in[7];
  const float* bw = (const float*)d_in[8];

  const size_t mat = (size_t)SEQ * DIM;
  const size_t nw = (size_t)DIM * DIM;
  if (ws_size < 4 * mat * sizeof(u16)) {
    fprintf(stderr, "kernel_launch: ws too small (%zu)\n", ws_size);
    return;
  }
  u16* Qb = (u16*)d_ws;
  u16* Kb = Qb + mat;
  u16* Vtb = Kb + mat;     // [768][4096]
  u16* AOb = Vtb + mat;    // also xb (sequentially dead)
  u16* xb = AOb;
  u16* wqb = (u16*)d_out;  // d_out as scratch during QKV+attn phases
  u16* wkb = wqb + nw;
  u16* wvb = wkb + nw;
  u16* wwb = Kb;           // K dead after attn

  prep_all<<<dim3(2400), dim3(256), 0, stream>>>(x, wq, wk, wv, xb, wqb, wkb, wvb);
  qkv_gemm<<<dim3(768), dim3(256), 0, stream>>>(xb, wqb, wkb, wvb, bq, bk, bv, Qb, Kb, Vtb);
  attn_kernel<<<dim3(768), dim3(256), 0, stream>>>(Qb, Kb, Vtb, AOb);
  prep_one<<<dim3(288), dim3(256), 0, stream>>>(ww, wwb);
  out_gemm<<<dim3(768), dim3(256), 0, stream>>>(AOb, wwb, bw, (float*)d_out);
}